// Round 6
// baseline (320.593 us; speedup 1.0000x reference)
//
#include <hip/hip_runtime.h>

typedef unsigned short ushort_t;
typedef unsigned int   uint_t;
typedef __attribute__((ext_vector_type(8)))  short  short8;
typedef __attribute__((ext_vector_type(4)))  float  float4v;
typedef __attribute__((ext_vector_type(16))) float  f32x16;
typedef __attribute__((ext_vector_type(4)))  uint_t uint4v;
typedef __attribute__((ext_vector_type(2)))  uint_t uint2v;

#define B_    16
#define CIN_  320
#define COUT_ 320
#define NLORA 50
#define R_    4
#define NCH   10                       // 32-ch chunks

// x_pad: [B][10][66][66][32] bf16
#define XCHUNK (66*66*32)              // 139,392 elems per (b,cc)
// wb16:  [10][9][320][32] bf16 (batch-independent)
#define WCHUNK (9*COUT_*32)            // 92,160 elems per chunk
// dwn_eff: [B][10][9][16][32] bf16
#define DCHUNK (9*16*32)
// down: [B][4][64][64] fp32

// workspace byte offsets
#define WB16_OFF  44605440ULL
#define DWNE_OFF  46448640ULL
#define DOWN_OFF  47923200ULL

__device__ __forceinline__ ushort_t bf16rne(float f) {
  uint_t u = __float_as_uint(f);
  u = (u + 0x7FFFu + ((u >> 16) & 1u)) >> 16;
  return (ushort_t)u;
}

__device__ __forceinline__ void gld16(const ushort_t* g, ushort_t* l) {
  __builtin_amdgcn_global_load_lds(
      (const __attribute__((address_space(1))) void*)g,
      (__attribute__((address_space(3))) void*)l,
      16, 0, 0);
}

__device__ __forceinline__ void lora_idx(const void* lora, int b, int* l_out,
                                         float* act_out) {
  const int* p32 = (const int*)lora;
  bool odd0 = true;
  #pragma unroll
  for (int i = 1; i < 16; i += 2) odd0 = odd0 && (p32[i] == 0);
  long long raw = odd0 ? ((const long long*)lora)[b] : (long long)p32[b];
  long long idx = (raw >= 0) ? (raw >> 2) : -(((-raw) + 3) >> 2);   // floor/4
  *act_out = (idx >= 0) ? 1.0f : 0.0f;                              // SCALE==1
  *l_out = (int)(idx < 0 ? 0 : (idx > (NLORA - 1) ? (NLORA - 1) : idx));
}

// ---------------------------------------------------------------------------
// Kernel 1: x [B][C][H][W] fp32 -> x_pad [B][C/32][66][66][32] bf16.
// (unchanged from round 5 — verified)
// ---------------------------------------------------------------------------
__global__ __launch_bounds__(256)
void pad_convert(const float* __restrict__ x, ushort_t* __restrict__ x_pad) {
  __shared__ float t[64][65];
  const int cc  = blockIdx.x;
  const int h   = blockIdx.y;
  const int b   = blockIdx.z;
  const int tid = threadIdx.x;
  #pragma unroll
  for (int it = 0; it < 4; ++it) {
    int idx = it * 256 + tid;
    int cl = idx >> 4, w4 = (idx & 15) * 4;
    float4v v = *(const float4v*)(x +
        (((size_t)(b * CIN_ + cc * 64 + cl)) * 64 + h) * 64 + w4);
    t[cl][w4] = v[0]; t[cl][w4 + 1] = v[1];
    t[cl][w4 + 2] = v[2]; t[cl][w4 + 3] = v[3];
  }
  __syncthreads();
  #pragma unroll
  for (int it = 0; it < 4; ++it) {
    int j  = it * 256 + tid;
    int cq = j & 15, wl = j >> 4;
    int cl = cq * 4;
    uint_t u0 = (uint_t)bf16rne(t[cl][wl])     | ((uint_t)bf16rne(t[cl + 1][wl]) << 16);
    uint_t u1 = (uint_t)bf16rne(t[cl + 2][wl]) | ((uint_t)bf16rne(t[cl + 3][wl]) << 16);
    int chunk = cc * 2 + (cl >> 5);
    uint2v u; u[0] = u0; u[1] = u1;
    *(uint2v*)(x_pad + (((size_t)(b * NCH + chunk) * 66 + (h + 1)) * 66 + (wl + 1)) * 32
               + (cl & 31)) = u;
  }
  if (h == 0) {
    #pragma unroll
    for (int s = 0; s < 2; ++s) {
      ushort_t* base = x_pad + (size_t)(b * NCH + cc * 2 + s) * XCHUNK;
      for (int g = tid; g < 528; g += 256) {
        int r = (g >= 264) ? 1 : 0;
        int g2 = g - r * 264;
        int col = g2 >> 2, qg = g2 & 3;
        *(uint4v*)(base + ((size_t)(r * 65) * 66 + col) * 32 + qg * 8) = (uint4v)0u;
      }
      for (int g = tid; g < 512; g += 256) {
        int row = 1 + (g >> 3);
        int col = ((g >> 2) & 1) * 65;
        int qg  = g & 3;
        *(uint4v*)(base + ((size_t)row * 66 + col) * 32 + qg * 8) = (uint4v)0u;
      }
    }
  }
}

// ---------------------------------------------------------------------------
// Kernel 2a: conv_w fp32 -> wb16 [10][9][320][32] bf16 (unchanged)
// ---------------------------------------------------------------------------
__global__ __launch_bounds__(512)
void wconv(const float* __restrict__ conv_w, ushort_t* __restrict__ wb16) {
  int idx = blockIdx.x * 512 + threadIdx.x;
  int c5 = idx & 31;
  int o  = (idx >> 5) % COUT_;
  int rest = idx / (COUT_ * 32);
  int tap = rest % 9, chunk = rest / 9;
  wb16[idx] = bf16rne(conv_w[((size_t)o * CIN_ + chunk * 32 + c5) * 9 + tap]);
}

// ---------------------------------------------------------------------------
// Kernel 2b: down_w -> dwn_eff (unchanged)
// ---------------------------------------------------------------------------
__global__ __launch_bounds__(512)
void dwnconv(const float* __restrict__ down_w, const void* __restrict__ lora,
             ushort_t* __restrict__ dwn_eff) {
  const int b = blockIdx.x;
  int l; float act;
  lora_idx(lora, b, &l, &act);
  ushort_t* dst = dwn_eff + (size_t)b * (NCH * DCHUNK);
  const float* src = down_w + (size_t)l * (R_ * CIN_ * 9);
  for (int it = 0; it < 90; ++it) {
    int idx = it * 512 + threadIdx.x;
    int c5 = idx & 31;
    int r  = (idx >> 5) & 15;
    int rest = idx >> 9;
    int tap = rest % 9, chunk = rest / 9;
    float v = (r < R_) ? act * src[((size_t)(r * CIN_) + chunk * 32 + c5) * 9 + tap]
                       : 0.0f;
    dst[idx] = bf16rne(v);
  }
}

// ---------------------------------------------------------------------------
// Kernel 3: lora_down — rank-4 conv (unchanged from round 5 — verified)
// ---------------------------------------------------------------------------
#define LXG    1360
#define LXGP   1408
#define LWG    576
#define LTOTG  2048
#define LBUF_B (LTOTG * 16)

__global__ __launch_bounds__(512)
void lora_down(const ushort_t* __restrict__ x_pad, const ushort_t* __restrict__ dwn_eff,
               float* __restrict__ down) {
  __shared__ __align__(16) char smem[2 * LBUF_B];

  const int tid = threadIdx.x;
  const int lin = blockIdx.x;
  const int b   = lin >> 4;
  const int hw  = lin & 15;
  const int h0  = (hw & 7) * 8;
  const int w0  = (hw >> 3) * 32;

  const int wv = tid >> 6;
  const int la = tid & 15;
  const int q  = (tid >> 4) & 3;

  const ushort_t* psrc[4];
  int step[4];
  #pragma unroll
  for (int r = 0; r < 4; ++r) {
    int g = r * 512 + tid;
    if (g < LXGP) {
      int gx = (g < LXG) ? g : (LXG - 1);
      int qq = gx & 3, t = gx >> 2;
      int hh = t / 34, ww = t - hh * 34;
      psrc[r] = x_pad + (size_t)b * NCH * XCHUNK
              + (((h0 + hh) * 66 + (w0 + ww)) * 32 + (qq ^ ((ww >> 1) & 3)) * 8);
      step[r] = XCHUNK;
    } else {
      int gw = g - LXGP;
      if (gw > LWG - 1) gw = LWG - 1;
      int qq = gw & 3, t2 = gw >> 2;
      int rr = t2 & 15, tap = t2 >> 4;
      psrc[r] = dwn_eff + (size_t)b * NCH * DCHUNK
              + ((tap * 16 + rr) * 32 + (qq ^ ((rr >> 1) & 3)) * 8);
      step[r] = DCHUNK;
    }
  }

  const char* ax0[3]; const char* ax1[3];
  #pragma unroll
  for (int kw = 0; kw < 3; ++kw) {
    int base = (wv * 34 + la + kw) * 64 + (q ^ (((la + kw) >> 1) & 3)) * 16;
    ax0[kw] = smem + base;
    ax1[kw] = smem + LBUF_B + base;
  }
  const int bfb = 22528 + la * 64 + (q ^ ((la >> 1) & 3)) * 16;
  const char* aw0 = smem + bfb;
  const char* aw1 = smem + LBUF_B + bfb;

  float4v acc[2];
  acc[0] = (float4v)0.0f; acc[1] = (float4v)0.0f;

  auto STAGE = [&](int sel) {
    ushort_t* bufb = (ushort_t*)(smem + sel * LBUF_B);
    #pragma unroll
    for (int r = 0; r < 4; ++r) {
      gld16(psrc[r], bufb + (r * 512 + wv * 64) * 8);
      psrc[r] += step[r];
    }
  };

  auto PHASE = [&](const char* axA, const char* axB, const char* axC,
                   const char* aw, bool do_stage, int sel_next) {
    __builtin_amdgcn_s_barrier();
    if (do_stage) STAGE(sel_next);
    __builtin_amdgcn_sched_barrier(0);
    if (do_stage) asm volatile("s_waitcnt vmcnt(4)" ::: "memory");
    else          asm volatile("s_waitcnt vmcnt(0)" ::: "memory");
    __builtin_amdgcn_sched_barrier(0);
    __builtin_amdgcn_s_barrier();
    __builtin_amdgcn_s_setprio(1);
    #pragma unroll
    for (int tap = 0; tap < 9; ++tap) {
      const int kh = tap / 3, kw = tap - kh * 3;
      const char* ax = (kw == 0) ? axA : ((kw == 1) ? axB : axC);
      short8 bf = *(const short8*)(aw + tap * 1024);
      #pragma unroll
      for (int i = 0; i < 2; ++i) {
        short8 af = *(const short8*)(ax + kh * 2176 + i * 1024);
        acc[i] = __builtin_amdgcn_mfma_f32_16x16x32_bf16(af, bf, acc[i], 0, 0, 0);
      }
    }
    __builtin_amdgcn_s_setprio(0);
  };

  STAGE(0);
  #pragma unroll
  for (int tp = 0; tp < 5; ++tp) {
    PHASE(ax0[0], ax0[1], ax0[2], aw0, true,    1);
    PHASE(ax1[0], ax1[1], ax1[2], aw1, tp < 4,  0);
  }

  if (la < R_) {
    #pragma unroll
    for (int i = 0; i < 2; ++i)
      *(float4v*)(down + (((size_t)(b * R_ + la) * 64 + h0 + wv) * 64)
                  + w0 + i * 16 + q * 4) = acc[i];
  }
}

// ---------------------------------------------------------------------------
// Kernel 4: main conv — 32x32x16 MFMA, wave tile 64w x 64o (halved LDS
// traffic: 0.5 KB/MFMA), K-chunks of 16 ch (20 chunks), 2x40,960 B LDS ->
// 2 blocks/CU. Block tile 8h x 64w x 64o; grid 640, XCD-bijective.
// Swizzle: 16-B slot g2 ^= (pos>>2)&1 — conflict-free per 8-lane group —
// applied on gld16 SOURCE and ds_read (both sides). vmcnt(5) exact.
// ---------------------------------------------------------------------------
__global__ __launch_bounds__(512, 4)
void conv_main(const ushort_t* __restrict__ x_pad, const ushort_t* __restrict__ wb16,
               const float* __restrict__ conv_b, const float* __restrict__ up_w,
               const float* __restrict__ down, const void* __restrict__ lora,
               float* __restrict__ out) {
  __shared__ __align__(16) char smem[81920];

  const int tid = threadIdx.x;
  const int lin = blockIdx.x;                        // 0..639
  const int wg  = (lin & 7) * 80 + (lin >> 3);       // XCD-bijective
  const int b   = wg / 40;
  const int rr  = wg - b * 40;
  const int ht  = rr / 5;
  const int oc  = rr - ht * 5;
  const int h0  = ht * 8;
  const int o0  = oc * 64;

  const int wv  = tid >> 6;          // wave = output row
  const int l31 = tid & 31;
  const int l5  = (tid >> 5) & 1;    // MFMA k-half

  // staging sources (pre-swizzled source = inverse of read swizzle)
  const ushort_t* psrc[5];
  int stepOdd[5];
  #pragma unroll
  for (int r = 0; r < 5; ++r) {
    int g = r * 512 + tid;
    if (g > 2471) g = 2471;                          // dummies dup last W granule
    if (g < 1320) {                                  // x: (hh,ww) pairs of 16-B slots
      int g2 = g & 1, t = g >> 1;
      int hh = t / 66, ww = t - hh * 66;
      int sq = g2 ^ ((ww >> 2) & 1);
      psrc[r] = x_pad + (size_t)b * (NCH * XCHUNK)
              + (((h0 + hh) * 66 + ww) * 32 + sq * 8);
      stepOdd[r] = XCHUNK - 16;
    } else {                                         // W: (tap,o) pairs
      int gw = g - 1320;
      int g2 = gw & 1, t2 = gw >> 1;
      int o = t2 & 63, tap = t2 >> 6;
      int sq = g2 ^ ((o >> 2) & 1);
      psrc[r] = wb16 + (((size_t)tap * COUT_ + o0 + o) * 32 + sq * 8);
      stepOdd[r] = WCHUNK - 16;
    }
  }

  // hoisted LDS read byte-offsets (within a buffer)
  int axo[3];
  #pragma unroll
  for (int kw = 0; kw < 3; ++kw)
    axo[kw] = (wv * 66 + l31 + kw) * 32 + (l5 ^ (((l31 + kw) >> 2) & 1)) * 16;
  const int awo = 21120 + l31 * 32 + (l5 ^ ((l31 >> 2) & 1)) * 16;

  f32x16 acc00 = (f32x16)0.0f, acc01 = (f32x16)0.0f;
  f32x16 acc10 = (f32x16)0.0f, acc11 = (f32x16)0.0f;

  auto STAGE = [&](int sel, bool evenAdv) {
    ushort_t* bb = (ushort_t*)(smem + sel * 40960);
    #pragma unroll
    for (int r = 0; r < 5; ++r) {
      gld16(psrc[r], bb + (r * 512 + wv * 64) * 8);
      psrc[r] += evenAdv ? 16 : stepOdd[r];
    }
  };

  auto PHASE = [&](int rb, bool stage, bool evenAdv) {
    asm volatile("" ::: "memory");
    __builtin_amdgcn_s_barrier();
    if (stage) STAGE(rb ^ 1, evenAdv);
    __builtin_amdgcn_sched_barrier(0);
    if (stage) asm volatile("s_waitcnt vmcnt(5)" ::: "memory");
    else       asm volatile("s_waitcnt vmcnt(0)" ::: "memory");
    __builtin_amdgcn_sched_barrier(0);
    __builtin_amdgcn_s_barrier();
    asm volatile("" ::: "memory");
    const char* bb = smem + rb * 40960;
    __builtin_amdgcn_s_setprio(1);
    #pragma unroll
    for (int tap = 0; tap < 9; ++tap) {
      const int kh = tap / 3, kw = tap - kh * 3;
      short8 bf0 = *(const short8*)(bb + awo + tap * 2048);
      short8 bf1 = *(const short8*)(bb + awo + tap * 2048 + 1024);
      short8 af0 = *(const short8*)(bb + axo[kw] + kh * 2112);
      short8 af1 = *(const short8*)(bb + axo[kw] + kh * 2112 + 1024);
      acc00 = __builtin_amdgcn_mfma_f32_32x32x16_bf16(af0, bf0, acc00, 0, 0, 0);
      acc01 = __builtin_amdgcn_mfma_f32_32x32x16_bf16(af0, bf1, acc01, 0, 0, 0);
      acc10 = __builtin_amdgcn_mfma_f32_32x32x16_bf16(af1, bf0, acc10, 0, 0, 0);
      acc11 = __builtin_amdgcn_mfma_f32_32x32x16_bf16(af1, bf1, acc11, 0, 0, 0);
    }
    __builtin_amdgcn_s_setprio(0);
  };

  STAGE(0, true);                    // chunk 0; advance 0->1 (+16)
  for (int tp = 0; tp < 10; ++tp) {
    PHASE(0, true,    false);        // compute even chunk, stage odd, adv odd->even
    PHASE(1, tp < 9,  true);         // compute odd chunk, stage even, adv even->odd
  }

  // Epilogue: direct stores from 32x32 C-fragments + bias + fused LoRA up.
  // C/D: col(o)=lane&31, row(w)=(reg&3)+8*(reg>>2)+4*(lane>>5)
  int l; float act;
  lora_idx(lora, b, &l, &act);
  const float* upb = up_w + (size_t)l * (COUT_ * R_);
  const int h = h0 + wv;
  const int row4 = l5 * 4;
  const float* dbase = down + (size_t)b * (R_ * 4096) + h * 64;
  float4v u0 = *(const float4v*)(upb + (o0 + l31) * R_);
  float4v u1 = *(const float4v*)(upb + (o0 + 32 + l31) * R_);
  const float bias0 = conv_b[o0 + l31];
  const float bias1 = conv_b[o0 + 32 + l31];
  float* ob0 = out + (((size_t)(b * COUT_ + o0 + l31)) * 64 + h) * 64;
  float* ob1 = out + (((size_t)(b * COUT_ + o0 + 32 + l31)) * 64 + h) * 64;
  #pragma unroll
  for (int i = 0; i < 2; ++i) {
    #pragma unroll
    for (int qd = 0; qd < 4; ++qd) {
      const int wl = i * 32 + qd * 8 + row4;
      float4v d0 = *(const float4v*)(dbase + 0 * 4096 + wl);
      float4v d1 = *(const float4v*)(dbase + 1 * 4096 + wl);
      float4v d2 = *(const float4v*)(dbase + 2 * 4096 + wl);
      float4v d3 = *(const float4v*)(dbase + 3 * 4096 + wl);
      {
        const f32x16& A = (i == 0) ? acc00 : acc10;
        float4v v;
        v[0] = A[qd * 4 + 0]; v[1] = A[qd * 4 + 1];
        v[2] = A[qd * 4 + 2]; v[3] = A[qd * 4 + 3];
        v += bias0;
        v += u0[0] * d0 + u0[1] * d1 + u0[2] * d2 + u0[3] * d3;
        *(float4v*)(ob0 + wl) = v;
      }
      {
        const f32x16& A = (i == 0) ? acc01 : acc11;
        float4v v;
        v[0] = A[qd * 4 + 0]; v[1] = A[qd * 4 + 1];
        v[2] = A[qd * 4 + 2]; v[3] = A[qd * 4 + 3];
        v += bias1;
        v += u1[0] * d0 + u1[1] * d1 + u1[2] * d2 + u1[3] * d3;
        *(float4v*)(ob1 + wl) = v;
      }
    }
  }
}

// ---------------------------------------------------------------------------
extern "C" void kernel_launch(void* const* d_in, const int* in_sizes, int n_in,
                              void* d_out, int out_size, void* d_ws, size_t ws_size,
                              hipStream_t stream) {
  const float* x      = (const float*)d_in[0];
  const float* conv_w = (const float*)d_in[1];
  const float* conv_b = (const float*)d_in[2];
  const float* down_w = (const float*)d_in[3];
  const float* up_w   = (const float*)d_in[4];
  const void*  lora   = d_in[5];
  float* out = (float*)d_out;

  ushort_t* x_pad   = (ushort_t*)d_ws;
  ushort_t* wb16    = (ushort_t*)((char*)d_ws + WB16_OFF);
  ushort_t* dwn_eff = (ushort_t*)((char*)d_ws + DWNE_OFF);
  float*    down    = (float*)((char*)d_ws + DOWN_OFF);

  pad_convert<<<dim3(5, 64, 16), 256, 0, stream>>>(x, x_pad);
  wconv      <<<dim3(1800),      512, 0, stream>>>(conv_w, wb16);
  dwnconv    <<<dim3(16),        512, 0, stream>>>(down_w, lora, dwn_eff);
  lora_down  <<<dim3(256),       512, 0, stream>>>(x_pad, dwn_eff, down);
  conv_main  <<<dim3(640),       512, 0, stream>>>(x_pad, wb16, conv_b, up_w,
                                                   down, lora, out);
}